// Round 4
// baseline (342.117 us; speedup 1.0000x reference)
//
#include <hip/hip_runtime.h>

#define NN 16384
#define MM 16384
#define DD 8
#define DV 16
#define R 8                     // rows per wave
#define WAVES 4
#define ROWS_BLK (R * WAVES)    // 32 rows per block
#define JSPLIT 2
#define JCHUNK (MM / JSPLIT)    // 8192
#define TJ 128                  // j-tile staged in LDS
#define JITER (JCHUNK / TJ)     // 64

typedef float v2f __attribute__((ext_vector_type(2)));

// Explicit packed fp32 (VOP3P): 2 FLOP/lane/cycle-pair — required for fp32 peak.
static __device__ __forceinline__ v2f pk_fma(v2f a, v2f b, v2f c) {
    v2f d;
    asm("v_pk_fma_f32 %0, %1, %2, %3" : "=v"(d) : "v"(a), "v"(b), "v"(c));
    return d;
}
static __device__ __forceinline__ v2f pk_mul(v2f a, v2f b) {
    v2f d;
    asm("v_pk_mul_f32 %0, %1, %2" : "=v"(d) : "v"(a), "v"(b));
    return d;
}

__global__ __launch_bounds__(256) void prep_sy(const float* __restrict__ ls,
                                               const float* __restrict__ y,
                                               float* __restrict__ sy) {
    int j = blockIdx.x * 256 + threadIdx.x;
    float s = 0.f;
#pragma unroll
    for (int d = 0; d < DD; ++d) {
        float yv = y[j * DD + d];
        s = fmaf(ls[d] * yv, yv, s);
    }
    sy[j] = s;
}

// j-tiles double-buffered in LDS (one barrier/iter, register prefetch issued
// during compute so the barrier's vmcnt drain is latency-free). Plane (SoA)
// LDS layout → stride-16B ds_read_b128, conflict-free. Packed fp32 math.
__global__ __launch_bounds__(256, 2) void matern_main(const float* __restrict__ ls,
                                                      const float* __restrict__ x,
                                                      const float* __restrict__ y,
                                                      const float* __restrict__ b,
                                                      const float* __restrict__ sy,
                                                      float* __restrict__ out) {
    const int t = threadIdx.x;
    const int lane = t & 63;
    const int wave = t >> 6;
    const int rowbase = blockIdx.x * ROWS_BLK + wave * R;
    const int jbeg = blockIdx.y * JCHUNK;

    // +1 float4 pad per plane: staggers plane base banks for staging writes;
    // within-plane reads stay contiguous (conflict-free).
    __shared__ float4 yT[2][2][TJ + 1];   // [buf][half][j]  y[j][0:4], y[j][4:8]
    __shared__ float4 bT[2][4][TJ + 1];   // [buf][k][j]     b[j][4k:4k+4]
    __shared__ float  syT[2][TJ];

    // Wave-uniform per-row data: xls[r][d] = ls_d * x_rd ; sxr = sum ls_d x_rd^2
    v2f xls[R][4];
    float sxr[R];
    {
        float lsv[DD];
#pragma unroll
        for (int d = 0; d < DD; ++d) lsv[d] = ls[d];
#pragma unroll
        for (int r = 0; r < R; ++r) {
            const float* xp = x + (size_t)(rowbase + r) * DD;
            float s = 0.f;
#pragma unroll
            for (int dd = 0; dd < 4; ++dd) {
                float x0 = xp[2 * dd], x1 = xp[2 * dd + 1];
                float xl0 = lsv[2 * dd] * x0, xl1 = lsv[2 * dd + 1] * x1;
                xls[r][dd].x = xl0;
                xls[r][dd].y = xl1;
                s = fmaf(xl0, x0, s);
                s = fmaf(xl1, x1, s);
            }
            sxr[r] = s;
        }
    }

    const float c1 = 2.23606797749979f;       // sqrt(5)
    const float c2 = 1.2909944487358056f;     // sqrt(5/3)
    const float c3 = -3.2259641843312987f;    // -sqrt(5)*log2(e)

    v2f acc[R][8];
#pragma unroll
    for (int r = 0; r < R; ++r)
#pragma unroll
        for (int v = 0; v < 8; ++v) acc[r][v] = (v2f){0.f, 0.f};

    const float4* y4 = (const float4*)y;
    const float4* b4 = (const float4*)b;

    // Prefetch tile 0
    float4 py, pb0, pb1;
    float psy;
    {
        const int jt = jbeg;
        py  = y4[(size_t)jt * 2 + t];
        pb0 = b4[(size_t)jt * 4 + t];
        pb1 = b4[(size_t)jt * 4 + t + 256];
        psy = sy[jt + (t & 127)];
    }

#pragma unroll 1
    for (int it = 0; it < JITER; ++it) {
        const int buf = it & 1;
        // Stage prefetched regs into LDS[buf]
        yT[buf][t & 1][t >> 1] = py;
        bT[buf][t & 3][t >> 2] = pb0;
        {
            const int u = t + 256;
            bT[buf][u & 3][u >> 2] = pb1;
        }
        if (t < 128) syT[buf][t] = psy;
        __syncthreads();

        // Prefetch next tile (consumed next iter — ~900 cyc of latency cover)
        if (it + 1 < JITER) {
            const int jt = jbeg + (it + 1) * TJ;
            py  = y4[(size_t)jt * 2 + t];
            pb0 = b4[(size_t)jt * 4 + t];
            pb1 = b4[(size_t)jt * 4 + t + 256];
            psy = sy[jt + (t & 127)];
        }

        // Compute on LDS[buf]
#pragma unroll
        for (int sub = 0; sub < 2; ++sub) {
            const int jl = lane + 64 * sub;
            float4 ya4 = yT[buf][0][jl];
            float4 yb4 = yT[buf][1][jl];
            float syv = syT[buf][jl];
            float4 q0 = bT[buf][0][jl];
            float4 q1 = bT[buf][1][jl];
            float4 q2 = bT[buf][2][jl];
            float4 q3 = bT[buf][3][jl];
            v2f ya01 = {ya4.x, ya4.y}, ya23 = {ya4.z, ya4.w};
            v2f yb01 = {yb4.x, yb4.y}, yb23 = {yb4.z, yb4.w};
            v2f bb[8] = {{q0.x, q0.y}, {q0.z, q0.w}, {q1.x, q1.y}, {q1.z, q1.w},
                         {q2.x, q2.y}, {q2.z, q2.w}, {q3.x, q3.y}, {q3.z, q3.w}};
#pragma unroll
            for (int r = 0; r < R; ++r) {
                v2f dd = pk_mul(xls[r][0], ya01);
                dd = pk_fma(xls[r][1], ya23, dd);
                dd = pk_fma(xls[r][2], yb01, dd);
                dd = pk_fma(xls[r][3], yb23, dd);
                float dot = dd.x + dd.y;
                float d2 = fmaf(-2.f, dot, sxr[r] + syv);
                d2 = fmaxf(d2, 0.f);
                float rr = __builtin_amdgcn_sqrtf(d2);
                float e = __builtin_amdgcn_exp2f(c3 * rr);
                float k = fmaf(c2, d2, fmaf(c1, rr, 1.f)) * e;
                v2f k2 = {k, k};
#pragma unroll
                for (int v = 0; v < 8; ++v) acc[r][v] = pk_fma(k2, bb[v], acc[r][v]);
            }
        }
        __syncthreads();
    }

    // Butterfly-reduce each accumulator across the 64 lanes.
#pragma unroll
    for (int r = 0; r < R; ++r)
#pragma unroll
        for (int v = 0; v < 8; ++v) {
            float px = acc[r][v].x, py2 = acc[r][v].y;
#pragma unroll
            for (int off = 32; off > 0; off >>= 1) {
                px += __shfl_xor(px, off, 64);
                py2 += __shfl_xor(py2, off, 64);
            }
            acc[r][v].x = px;
            acc[r][v].y = py2;
        }

    if (lane == 0) {
#pragma unroll
        for (int r = 0; r < R; ++r) {
            float* op = out + (size_t)(rowbase + r) * DV;
#pragma unroll
            for (int v = 0; v < 8; ++v) {
                atomicAdd(op + 2 * v, acc[r][v].x);
                atomicAdd(op + 2 * v + 1, acc[r][v].y);
            }
        }
    }
}

extern "C" void kernel_launch(void* const* d_in, const int* in_sizes, int n_in,
                              void* d_out, int out_size, void* d_ws, size_t ws_size,
                              hipStream_t stream) {
    const float* ls = (const float*)d_in[0];
    const float* x  = (const float*)d_in[1];
    const float* y  = (const float*)d_in[2];
    const float* b  = (const float*)d_in[3];
    float* out = (float*)d_out;
    float* sy  = (float*)d_ws;   // 16384 floats = 64 KB scratch

    hipMemsetAsync(d_out, 0, (size_t)out_size * sizeof(float), stream);
    prep_sy<<<MM / 256, 256, 0, stream>>>(ls, y, sy);
    matern_main<<<dim3(NN / ROWS_BLK, JSPLIT), 256, 0, stream>>>(ls, x, y, b, sy, out);
}

// Round 5
// 170.568 us; speedup vs baseline: 2.0057x; 2.0057x over previous
//
#include <hip/hip_runtime.h>
#include <stdint.h>

#define NN 16384
#define MM 16384
#define DD 8
#define DV 16
#define WAVES 4
#define MT 2                        // 16-row m-tiles per wave
#define ROWS_WAVE (MT * 16)         // 32
#define ROWS_BLK (WAVES * ROWS_WAVE)// 128
#define JSPLIT 8
#define JCHUNK (MM / JSPLIT)        // 2048
#define J32 (JCHUNK / 32)           // 64 iterations per block

typedef short bf8 __attribute__((ext_vector_type(8)));   // 8 bf16 (4 VGPR)
typedef float f32x4 __attribute__((ext_vector_type(4))); // MFMA C/D

__device__ __forceinline__ unsigned short f2bf(float f) {
    union { float f; uint32_t u; } c; c.f = f;
    uint32_t u = c.u + 0x7FFF + ((c.u >> 16) & 1);       // RNE
    return (unsigned short)(u >> 16);
}
__device__ __forceinline__ float bf2f(unsigned short h) {
    union { float f; uint32_t u; } c; c.u = ((uint32_t)h) << 16;
    return c.f;
}

// Precompute block-invariant MFMA fragments into d_ws:
//  ytbl[tile16][lane]: B-operand frag for S = Xls·Y^T, hi/lo packed in K:
//     k=0..7 -> y_hi, k=8..15 -> y_hi, k=16..23 -> y_lo, k=24..31 -> 0
//     (pairs with A-side quad sel hi,lo,hi,0: S = xh·yh + xl·yh + xh·yl ~ fp32 dot)
//  btbl[tile32][lane]: B-operand frag for out += K·B: B[k=quad*8+s][n]=bf16(b[j][n])
//  sy[j] = sum_d ls_d*y_jd^2
__global__ __launch_bounds__(64) void prep_frags(const float* __restrict__ ls,
                                                 const float* __restrict__ y,
                                                 const float* __restrict__ b,
                                                 bf8* __restrict__ ytbl,
                                                 bf8* __restrict__ btbl,
                                                 float* __restrict__ sy) {
    const int tile = blockIdx.x;      // 0..1023 (j16 tiles)
    const int lane = threadIdx.x;     // 0..63
    const int n = lane & 15, quad = lane >> 4;

    float lsv[DD];
#pragma unroll
    for (int d = 0; d < DD; ++d) lsv[d] = ls[d];

    const float* yr = y + (size_t)(tile * 16 + n) * DD;
    float syv = 0.f;
    bf8 fr;
#pragma unroll
    for (int d = 0; d < DD; ++d) {
        float yv = yr[d];
        syv = fmaf(lsv[d] * yv, yv, syv);
        unsigned short yh = f2bf(yv);
        unsigned short yl = f2bf(yv - bf2f(yh));
        fr[d] = (short)(quad == 3 ? 0 : (quad == 2 ? yl : yh));
    }
    ytbl[tile * 64 + lane] = fr;
    if (quad == 0) sy[tile * 16 + n] = syv;

    if (tile < MM / 32) {             // j32 tiles for phase B
        bf8 bfr;
#pragma unroll
        for (int s = 0; s < 8; ++s) {
            float bv = b[(size_t)(tile * 32 + quad * 8 + s) * DV + n];
            bfr[s] = (short)f2bf(bv);
        }
        btbl[tile * 64 + lane] = bfr;
    }
}

// Flash-style: per j32 tile, S = Xls·Y^T (MFMA, hi/lo split), VALU Matern
// transform in C/D layout, k -> bf16 -> wave-private LDS (C/D->A layout
// round trip, 80B padded rows), out-acc += K·B (MFMA). No __syncthreads in
// the loop: klds is wave-private, same-wave DS ordering via lgkmcnt.
__global__ __launch_bounds__(256, 4) void matern_mfma(const float* __restrict__ ls,
                                                      const float* __restrict__ x,
                                                      const bf8* __restrict__ ytbl,
                                                      const bf8* __restrict__ btbl,
                                                      const float* __restrict__ sy,
                                                      float* __restrict__ out) {
    const int t = threadIdx.x;
    const int lane = t & 63, wave = t >> 6;
    const int n = lane & 15, quad = lane >> 4;
    const int waverow = blockIdx.x * ROWS_BLK + wave * ROWS_WAVE;

    // [wave][mt][m][40]: 80B rows (16B-aligned, bank-spread: m*20 % 32 covers 8 banks)
    __shared__ __attribute__((aligned(16))) unsigned short klds[WAVES][MT][16][40];

    float lsv[DD];
#pragma unroll
    for (int d = 0; d < DD; ++d) lsv[d] = ls[d];

    // A-operand frags: lane holds A[m=lane&15][k=quad*8+s]; quad sel hi,lo,hi,0
    bf8 afrag[MT];
#pragma unroll
    for (int mt = 0; mt < MT; ++mt) {
        const float* xr = x + (size_t)(waverow + mt * 16 + n) * DD;
#pragma unroll
        for (int d = 0; d < DD; ++d) {
            float xls = lsv[d] * xr[d];
            unsigned short xh = f2bf(xls);
            unsigned short xl = f2bf(xls - bf2f(xh));
            afrag[mt][d] = (short)(quad == 3 ? 0 : (quad == 1 ? xl : xh));
        }
    }

    // sx for the C/D rows this lane owns: row = quad*4 + s
    float sxq[MT][4];
#pragma unroll
    for (int mt = 0; mt < MT; ++mt)
#pragma unroll
        for (int s = 0; s < 4; ++s) {
            const float* xr = x + (size_t)(waverow + mt * 16 + quad * 4 + s) * DD;
            float acc = 0.f;
#pragma unroll
            for (int d = 0; d < DD; ++d) acc = fmaf(lsv[d] * xr[d], xr[d], acc);
            sxq[mt][s] = acc;
        }

    const float c1 = 2.23606797749979f;      // sqrt(5)
    const float c2 = 1.2909944487358056f;    // sqrt(5/3)
    const float c3 = -3.2259641843312987f;   // -sqrt(5)*log2(e)

    f32x4 acc[MT];
#pragma unroll
    for (int mt = 0; mt < MT; ++mt) acc[mt] = (f32x4){0.f, 0.f, 0.f, 0.f};

    const int tile16base = blockIdx.y * (JCHUNK / 16);
    const int tile32base = blockIdx.y * (JCHUNK / 32);

#pragma unroll 1
    for (int it = 0; it < J32; ++it) {
        const int tl0 = tile16base + it * 2;
        bf8 yA = ytbl[tl0 * 64 + lane];
        bf8 yB = ytbl[(tl0 + 1) * 64 + lane];
        bf8 bb = btbl[(tile32base + it) * 64 + lane];
        float syA = sy[tl0 * 16 + n];
        float syB = sy[(tl0 + 1) * 16 + n];

#pragma unroll
        for (int mt = 0; mt < MT; ++mt) {
            f32x4 z = (f32x4){0.f, 0.f, 0.f, 0.f};
            f32x4 s0 = __builtin_amdgcn_mfma_f32_16x16x32_bf16(afrag[mt], yA, z, 0, 0, 0);
            f32x4 s1 = __builtin_amdgcn_mfma_f32_16x16x32_bf16(afrag[mt], yB, z, 0, 0, 0);
#pragma unroll
            for (int s = 0; s < 4; ++s) {
                {   // j-tile 0 -> klds cols 0..15
                    float d2 = fmaf(-2.f, s0[s], sxq[mt][s] + syA);
                    d2 = fmaxf(d2, 0.f);
                    float r = __builtin_amdgcn_sqrtf(d2);
                    float e = __builtin_amdgcn_exp2f(c3 * r);
                    float k = fmaf(c2, d2, fmaf(c1, r, 1.f)) * e;
                    klds[wave][mt][quad * 4 + s][n] = f2bf(k);
                }
                {   // j-tile 1 -> klds cols 16..31
                    float d2 = fmaf(-2.f, s1[s], sxq[mt][s] + syB);
                    d2 = fmaxf(d2, 0.f);
                    float r = __builtin_amdgcn_sqrtf(d2);
                    float e = __builtin_amdgcn_exp2f(c3 * r);
                    float k = fmaf(c2, d2, fmaf(c1, r, 1.f)) * e;
                    klds[wave][mt][quad * 4 + s][n + 16] = f2bf(k);
                }
            }
        }
        // C/D->A layout: lane reads A'[m=lane&15][k=quad*8+s] as one 16B LDS read
#pragma unroll
        for (int mt = 0; mt < MT; ++mt) {
            const bf8* kp = (const bf8*)&klds[wave][mt][n][quad * 8];
            acc[mt] = __builtin_amdgcn_mfma_f32_16x16x32_bf16(*kp, bb, acc[mt], 0, 0, 0);
        }
    }

    // Epilogue: D layout row=quad*4+s, col=n; JSPLIT partial sums via atomics
#pragma unroll
    for (int mt = 0; mt < MT; ++mt)
#pragma unroll
        for (int s = 0; s < 4; ++s) {
            const int row = waverow + mt * 16 + quad * 4 + s;
            atomicAdd(out + (size_t)row * DV + n, acc[mt][s]);
        }
}

extern "C" void kernel_launch(void* const* d_in, const int* in_sizes, int n_in,
                              void* d_out, int out_size, void* d_ws, size_t ws_size,
                              hipStream_t stream) {
    const float* ls = (const float*)d_in[0];
    const float* x  = (const float*)d_in[1];
    const float* y  = (const float*)d_in[2];
    const float* b  = (const float*)d_in[3];
    float* out = (float*)d_out;

    char* ws = (char*)d_ws;
    bf8*   ytbl = (bf8*)ws;                        // 1024*64*16B = 1 MB
    bf8*   btbl = (bf8*)(ws + (1 << 20));          // 512*64*16B  = 512 KB
    float* sy   = (float*)(ws + (1 << 20) + (512 << 10)); // 64 KB

    hipMemsetAsync(d_out, 0, (size_t)out_size * sizeof(float), stream);
    prep_frags<<<MM / 16, 64, 0, stream>>>(ls, y, b, ytbl, btbl, sy);
    matern_mfma<<<dim3(NN / ROWS_BLK, JSPLIT), 256, 0, stream>>>(ls, x, ytbl, btbl, sy, out);
}

// Round 9
// 162.421 us; speedup vs baseline: 2.1064x; 1.0502x over previous
//
#include <hip/hip_runtime.h>
#include <stdint.h>

#define NN 16384
#define MM 16384
#define DD 8
#define DV 16
#define WAVES 4
#define MT 2                        // 16-row m-tiles per wave
#define ROWS_WAVE (MT * 16)         // 32
#define ROWS_BLK (WAVES * ROWS_WAVE)// 128
#define JSPLIT 16
#define JCHUNK (MM / JSPLIT)        // 1024
#define J32 (JCHUNK / 32)           // 32 iterations per block

typedef short bf8 __attribute__((ext_vector_type(8)));   // 8 bf16 (4 VGPR)
typedef float f32x4 __attribute__((ext_vector_type(4))); // MFMA C/D

__device__ __forceinline__ unsigned short f2bf(float f) {
    union { float f; uint32_t u; } c; c.f = f;
    uint32_t u = c.u + 0x7FFF + ((c.u >> 16) & 1);       // RNE
    return (unsigned short)(u >> 16);
}
__device__ __forceinline__ float bf2f(unsigned short h) {
    union { float f; uint32_t u; } c; c.u = ((uint32_t)h) << 16;
    return c.f;
}

// Precompute block-invariant MFMA fragments into d_ws (R5-proven):
//  ytbl[tile16][lane]: B-operand frag for S = Xls·Y^T, hi/lo packed in K
//  btbl[tile32][lane]: B-operand frag for out += K·B (direct K-order)
//  sy[j] = sum_d ls_d*y_jd^2
__global__ __launch_bounds__(64) void prep_frags(const float* __restrict__ ls,
                                                 const float* __restrict__ y,
                                                 const float* __restrict__ b,
                                                 bf8* __restrict__ ytbl,
                                                 bf8* __restrict__ btbl,
                                                 float* __restrict__ sy) {
    const int tile = blockIdx.x;      // 0..1023 (j16 tiles)
    const int lane = threadIdx.x;     // 0..63
    const int n = lane & 15, quad = lane >> 4;

    float lsv[DD];
#pragma unroll
    for (int d = 0; d < DD; ++d) lsv[d] = ls[d];

    const float* yr = y + (size_t)(tile * 16 + n) * DD;
    float syv = 0.f;
    bf8 fr;
#pragma unroll
    for (int d = 0; d < DD; ++d) {
        float yv = yr[d];
        syv = fmaf(lsv[d] * yv, yv, syv);
        unsigned short yh = f2bf(yv);
        unsigned short yl = f2bf(yv - bf2f(yh));
        fr[d] = (short)(quad == 3 ? 0 : (quad == 2 ? yl : yh));
    }
    ytbl[tile * 64 + lane] = fr;
    if (quad == 0) sy[tile * 16 + n] = syv;

    if (tile < MM / 32) {             // j32 tiles for phase B
        bf8 bfr;
#pragma unroll
        for (int s = 0; s < 8; ++s) {
            float bv = b[(size_t)(tile * 32 + quad * 8 + s) * DV + n];
            bfr[s] = (short)f2bf(bv);
        }
        btbl[tile * 64 + lane] = bfr;
    }
}

// EXACT R5 structure (the proven-correct 170.6us PASS): per j32 tile,
// S = Xls·Y^T (MFMA, hi/lo split), scalar VALU Matern transform in C/D
// layout, k -> bf16 -> wave-private LDS (C/D->A round trip, 80B padded
// rows), out-acc += K·B (MFMA). No __syncthreads in the loop.
// Changes vs R5 (both occupancy-only): JSPLIT 8->16 (2048 blocks),
// __launch_bounds__ min-waves 4->8 (VGPR=36, LDS=10KB allow 8 blocks/CU).
__global__ __launch_bounds__(256, 8) void matern_mfma(const float* __restrict__ ls,
                                                      const float* __restrict__ x,
                                                      const bf8* __restrict__ ytbl,
                                                      const bf8* __restrict__ btbl,
                                                      const float* __restrict__ sy,
                                                      float* __restrict__ out) {
    const int t = threadIdx.x;
    const int lane = t & 63, wave = t >> 6;
    const int n = lane & 15, quad = lane >> 4;
    const int waverow = blockIdx.x * ROWS_BLK + wave * ROWS_WAVE;

    // [wave][mt][m][40]: 80B rows, 16B-aligned reads; <=2-way conflicts (free)
    __shared__ __attribute__((aligned(16))) unsigned short klds[WAVES][MT][16][40];

    float lsv[DD];
#pragma unroll
    for (int d = 0; d < DD; ++d) lsv[d] = ls[d];

    // A-operand frags: lane holds A[m=lane&15][k=quad*8+s]; quad sel hi,lo,hi,0
    bf8 afrag[MT];
#pragma unroll
    for (int mt = 0; mt < MT; ++mt) {
        const float* xr = x + (size_t)(waverow + mt * 16 + n) * DD;
#pragma unroll
        for (int d = 0; d < DD; ++d) {
            float xls = lsv[d] * xr[d];
            unsigned short xh = f2bf(xls);
            unsigned short xl = f2bf(xls - bf2f(xh));
            afrag[mt][d] = (short)(quad == 3 ? 0 : (quad == 1 ? xl : xh));
        }
    }

    // sx for the C/D rows this lane owns: row = quad*4 + s
    float sxq[MT][4];
#pragma unroll
    for (int mt = 0; mt < MT; ++mt)
#pragma unroll
        for (int s = 0; s < 4; ++s) {
            const float* xr = x + (size_t)(waverow + mt * 16 + quad * 4 + s) * DD;
            float acc = 0.f;
#pragma unroll
            for (int d = 0; d < DD; ++d) acc = fmaf(lsv[d] * xr[d], xr[d], acc);
            sxq[mt][s] = acc;
        }

    const float c1 = 2.23606797749979f;      // sqrt(5)
    const float c2 = 1.2909944487358056f;    // sqrt(5/3)
    const float c3 = -3.2259641843312987f;   // -sqrt(5)*log2(e)

    f32x4 acc[MT];
#pragma unroll
    for (int mt = 0; mt < MT; ++mt) acc[mt] = (f32x4){0.f, 0.f, 0.f, 0.f};

    const int tile16base = blockIdx.y * (JCHUNK / 16);
    const int tile32base = blockIdx.y * (JCHUNK / 32);

#pragma unroll 1
    for (int it = 0; it < J32; ++it) {
        const int tl0 = tile16base + it * 2;
        bf8 yA = ytbl[(size_t)tl0 * 64 + lane];
        bf8 yB = ytbl[(size_t)(tl0 + 1) * 64 + lane];
        bf8 bb = btbl[(size_t)(tile32base + it) * 64 + lane];
        float syA = sy[tl0 * 16 + n];
        float syB = sy[(tl0 + 1) * 16 + n];

#pragma unroll
        for (int mt = 0; mt < MT; ++mt) {
            f32x4 z = (f32x4){0.f, 0.f, 0.f, 0.f};
            f32x4 s0 = __builtin_amdgcn_mfma_f32_16x16x32_bf16(afrag[mt], yA, z, 0, 0, 0);
            f32x4 s1 = __builtin_amdgcn_mfma_f32_16x16x32_bf16(afrag[mt], yB, z, 0, 0, 0);
#pragma unroll
            for (int s = 0; s < 4; ++s) {
                {   // j-tile 0 -> klds cols 0..15
                    float d2 = fmaf(-2.f, s0[s], sxq[mt][s] + syA);
                    d2 = fmaxf(d2, 0.f);
                    float r = __builtin_amdgcn_sqrtf(d2);
                    float e = __builtin_amdgcn_exp2f(c3 * r);
                    float k = fmaf(c2, d2, fmaf(c1, r, 1.f)) * e;
                    klds[wave][mt][quad * 4 + s][n] = f2bf(k);
                }
                {   // j-tile 1 -> klds cols 16..31
                    float d2 = fmaf(-2.f, s1[s], sxq[mt][s] + syB);
                    d2 = fmaxf(d2, 0.f);
                    float r = __builtin_amdgcn_sqrtf(d2);
                    float e = __builtin_amdgcn_exp2f(c3 * r);
                    float k = fmaf(c2, d2, fmaf(c1, r, 1.f)) * e;
                    klds[wave][mt][quad * 4 + s][n + 16] = f2bf(k);
                }
            }
        }
        // C/D->A layout: lane reads A'[m=lane&15][k=quad*8+s] as one 16B LDS read
#pragma unroll
        for (int mt = 0; mt < MT; ++mt) {
            const bf8* kp = (const bf8*)&klds[wave][mt][n][quad * 8];
            acc[mt] = __builtin_amdgcn_mfma_f32_16x16x32_bf16(*kp, bb, acc[mt], 0, 0, 0);
        }
    }

    // Epilogue: D layout row=quad*4+s, col=n; JSPLIT partial sums via atomics
#pragma unroll
    for (int mt = 0; mt < MT; ++mt)
#pragma unroll
        for (int s = 0; s < 4; ++s) {
            const int row = waverow + mt * 16 + quad * 4 + s;
            atomicAdd(out + (size_t)row * DV + n, acc[mt][s]);
        }
}

extern "C" void kernel_launch(void* const* d_in, const int* in_sizes, int n_in,
                              void* d_out, int out_size, void* d_ws, size_t ws_size,
                              hipStream_t stream) {
    const float* ls = (const float*)d_in[0];
    const float* x  = (const float*)d_in[1];
    const float* y  = (const float*)d_in[2];
    const float* b  = (const float*)d_in[3];
    float* out = (float*)d_out;

    char* ws = (char*)d_ws;
    bf8*   ytbl = (bf8*)ws;                        // 1024*64*16B = 1 MB
    bf8*   btbl = (bf8*)(ws + (1 << 20));          // 512*64*16B  = 512 KB
    float* sy   = (float*)(ws + (1 << 20) + (512 << 10)); // 64 KB

    hipMemsetAsync(d_out, 0, (size_t)out_size * sizeof(float), stream);
    prep_frags<<<MM / 16, 64, 0, stream>>>(ls, y, b, ytbl, btbl, sy);
    matern_mfma<<<dim3(NN / ROWS_BLK, JSPLIT), 256, 0, stream>>>(ls, x, ytbl, btbl, sy, out);
}